// Round 7
// baseline (316.472 us; speedup 1.0000x reference)
//
#include <hip/hip_runtime.h>
#include <hip/hip_bf16.h>
#include <cmath>

#define B_   2
#define S_   2048
#define D_   1024
#define H_   16
#define DFF_ 4096
#define DH_  64
#define M_   (B_*S_)   // 4096 rows

typedef __bf16 bfx8 __attribute__((ext_vector_type(8)));
typedef __bf16 bfx4 __attribute__((ext_vector_type(4)));
typedef float  fx4  __attribute__((ext_vector_type(4)));

// ---------------------------------------------------------------- utilities
__device__ __forceinline__ void gload_lds16(const void* g, void* l) {
  __builtin_amdgcn_global_load_lds((__attribute__((address_space(1))) void*)(g),
                                   (__attribute__((address_space(3))) void*)(l),
                                   16, 0, 0);
}

// ------------------------------------------------------------- fp32 -> bf16
__global__ __launch_bounds__(256)
void to_bf16_kernel(const float* __restrict__ in, __bf16* __restrict__ out, int n) {
  int i = (blockIdx.x * 256 + threadIdx.x) * 4;
  if (i < n) {
    float4 v = *(const float4*)(in + i);
    bfx4 o;
    o[0] = (__bf16)v.x; o[1] = (__bf16)v.y; o[2] = (__bf16)v.z; o[3] = (__bf16)v.w;
    *(bfx4*)(out + i) = o;
  }
}

// --------------------------------------- W [R][C] f32 -> Wt [C][R] bf16
__global__ __launch_bounds__(256)
void transpose_conv_kernel(const float* __restrict__ in, __bf16* __restrict__ out,
                           int R, int C) {
  __shared__ float t[32][33];
  int r0 = blockIdx.y * 32, c0 = blockIdx.x * 32;
  int tx = threadIdx.x, ty = threadIdx.y;   // 32 x 8
#pragma unroll
  for (int j = 0; j < 4; ++j) {
    int r = ty + j * 8;
    t[r][tx] = in[(size_t)(r0 + r) * C + c0 + tx];
  }
  __syncthreads();
#pragma unroll
  for (int j = 0; j < 4; ++j) {
    int c = ty + j * 8;
    out[(size_t)(c0 + c) * R + r0 + tx] = (__bf16)t[tx][c];
  }
}

// ----------------------- V [B,S,H,DH] bf16 -> Vt [B,H,DH,S] bf16
__global__ __launch_bounds__(256)
void transpose_v_kernel(const __bf16* __restrict__ vb, __bf16* __restrict__ vt) {
  __shared__ __bf16 t[32][33];
  int bh = blockIdx.z;
  int b = bh >> 4, h = bh & 15;
  int s0 = blockIdx.x * 32, d0 = blockIdx.y * 32;
  int tx = threadIdx.x, ty = threadIdx.y;
#pragma unroll
  for (int j = 0; j < 4; ++j) {
    int s = ty + j * 8;
    t[s][tx] = vb[(size_t)((b * S_ + s0 + s) * H_ + h) * DH_ + d0 + tx];
  }
  __syncthreads();
#pragma unroll
  for (int j = 0; j < 4; ++j) {
    int d = ty + j * 8;
    vt[(size_t)(bh * DH_ + d0 + d) * S_ + s0 + tx] = t[tx][d];
  }
}

// --------------------------------------------------------------- GEMM core
// C[m][n] = sum_k A[m][k]*B[k][n] + bias[n].  A:[M][K] bf16, Bt:[N][K] bf16.
// MODE 0: bf16 out. 1: f32 out. 2: exact-GELU bf16 out.
// Block tile: 128 x TBN, BK=64, 256 threads (4 waves as 2x2).
template<int MODE, int TBN>
__device__ __forceinline__ void gemm_body(const __bf16* __restrict__ A,
                                          const __bf16* __restrict__ Bt,
                                          const float* __restrict__ bias,
                                          void* __restrict__ out,
                                          int Ndim, int Kdim,
                                          int m0, int n0,
                                          __bf16* As, __bf16* Bs) {
  const int tid  = threadIdx.x;
  const int lane = tid & 63;
  const int w    = tid >> 6;
  const int wm   = w >> 1, wn = w & 1;
  constexpr int NF = TBN / 32;          // N-fragments per wave

  fx4 acc[4][NF];
#pragma unroll
  for (int i = 0; i < 4; ++i)
#pragma unroll
    for (int j = 0; j < NF; ++j) acc[i][j] = {0.f, 0.f, 0.f, 0.f};

  const int KT = Kdim / 64;
  for (int kt = 0; kt < KT; ++kt) {
    __syncthreads();
    const int kb0 = kt * 64;
#pragma unroll
    for (int i = 0; i < 4; ++i) {            // A tile: 16 KB
      int o   = tid * 16 + i * 4096;
      int row = o >> 7, cb = o & 127;
      int cbs = cb ^ ((row & 7) << 4);
      gload_lds16((const char*)A + ((size_t)(m0 + row) * Kdim + kb0) * 2 + cbs,
                  (char*)As + o);
    }
#pragma unroll
    for (int i = 0; i < TBN / 32; ++i) {     // B tile: TBN*128 bytes
      int o   = tid * 16 + i * 4096;
      int row = o >> 7, cb = o & 127;
      int cbs = cb ^ ((row & 7) << 4);
      gload_lds16((const char*)Bt + ((size_t)(n0 + row) * Kdim + kb0) * 2 + cbs,
                  (char*)Bs + o);
    }
    __syncthreads();

#pragma unroll
    for (int kk = 0; kk < 2; ++kk) {
      bfx8 afr[4], bfr[NF];
      const int cb = kk * 64 + ((lane >> 4) << 4);
#pragma unroll
      for (int mf = 0; mf < 4; ++mf) {
        int row = wm * 64 + mf * 16 + (lane & 15);
        afr[mf] = *(const bfx8*)((const char*)As + row * 128 + (cb ^ ((row & 7) << 4)));
      }
#pragma unroll
      for (int nf = 0; nf < NF; ++nf) {
        int row = wn * (TBN / 2) + nf * 16 + (lane & 15);
        bfr[nf] = *(const bfx8*)((const char*)Bs + row * 128 + (cb ^ ((row & 7) << 4)));
      }
#pragma unroll
      for (int mf = 0; mf < 4; ++mf)
#pragma unroll
        for (int nf = 0; nf < NF; ++nf)
          acc[mf][nf] = __builtin_amdgcn_mfma_f32_16x16x32_bf16(afr[mf], bfr[nf],
                                                                acc[mf][nf], 0, 0, 0);
    }
  }

#pragma unroll
  for (int mf = 0; mf < 4; ++mf) {
#pragma unroll
    for (int nf = 0; nf < NF; ++nf) {
      int col = n0 + wn * (TBN / 2) + nf * 16 + (lane & 15);
      float bvl = bias[col];
#pragma unroll
      for (int r = 0; r < 4; ++r) {
        int rowg = m0 + wm * 64 + mf * 16 + ((lane >> 4) << 2) + r;
        float v = acc[mf][nf][r] + bvl;
        if (MODE == 2) v = 0.5f * v * (1.0f + erff(v * 0.70710678118654752f));
        if (MODE == 1) ((float*)out)[(size_t)rowg * Ndim + col] = v;
        else          ((__bf16*)out)[(size_t)rowg * Ndim + col] = (__bf16)v;
      }
    }
  }
}

template<int MODE, int TBN>
__global__ __launch_bounds__(256)
void gemm_kernel(const __bf16* __restrict__ A, const __bf16* __restrict__ Bt,
                 const float* __restrict__ bias, void* __restrict__ out,
                 int Ndim, int Kdim) {
  __shared__ alignas(16) __bf16 As[128 * 64];
  __shared__ alignas(16) __bf16 Bs[TBN * 64];
  gemm_body<MODE, TBN>(A, Bt, bias, out, Ndim, Kdim,
                       blockIdx.y * 128, blockIdx.x * TBN, As, Bs);
}

struct QKVArgs {
  const __bf16* A[3]; const __bf16* Bt[3]; const float* bias[3]; __bf16* out[3];
};

// fused QKV: blockIdx.z selects projection -> 768 blocks (3/CU)
__global__ __launch_bounds__(256)
void qkv_gemm_kernel(QKVArgs args, int Ndim, int Kdim) {
  __shared__ alignas(16) __bf16 As[128 * 64];
  __shared__ alignas(16) __bf16 Bs[128 * 64];
  int z = blockIdx.z;
  gemm_body<0, 128>(args.A[z], args.Bt[z], args.bias[z], (void*)args.out[z],
                    Ndim, Kdim, blockIdx.y * 128, blockIdx.x * 128, As, Bs);
}

// --------------------------------------------------------- flash attention
// Round-5 validated fenced body (swapped QK^T, lane-local stats, vector P
// write, lgkmcnt(0)+sched_barrier fence) in the 8-wave shell: 128 q-rows per
// block, 512 threads, wave w owns q-rows [16w,16w+16). grid (S/128, B*H).
__global__ __launch_bounds__(512)
void attn_kernel(const __bf16* __restrict__ Qb, const __bf16* __restrict__ Kb,
                 const __bf16* __restrict__ Vt, const float* __restrict__ mask,
                 __bf16* __restrict__ ctx) {
  __shared__ alignas(16) __bf16 Qs[128 * 64];    // 16 KB
  __shared__ alignas(16) __bf16 Ks[64 * 64];     //  8 KB
  __shared__ alignas(16) __bf16 Vs[64 * 64];     //  8 KB (rows = dh, cols = kv)
  __shared__ alignas(16) __bf16 Ps[8 * 16 * 64]; // 16 KB per-wave strips

  const int tid  = threadIdx.x;
  const int lane = tid & 63;
  const int w    = tid >> 6;          // 0..7
  const int g    = lane >> 4;         // 0..3
  const int ql   = lane & 15;
  const int bh   = blockIdx.y;
  const int b    = bh >> 4;
  const int h    = bh & 15;
  const int q0   = blockIdx.x * 128;

  // stage Q tile: 16 KB, 512 threads x 2 iters
  const size_t qbase = ((size_t)(b * S_) + q0) * D_ + h * DH_;
#pragma unroll
  for (int i = 0; i < 2; ++i) {
    int o   = tid * 16 + i * 8192;
    int row = o >> 7, cb = o & 127;
    int cbs = cb ^ ((row & 7) << 4);
    gload_lds16((const char*)Qb + (qbase + (size_t)row * D_) * 2 + cbs, (char*)Qs + o);
  }
  __syncthreads();

  bfx8 aq[2];   // Q fragment: row w*16+ql, k-halves (byte addressing = round-5)
  {
    int row = w * 16 + ql;
#pragma unroll
    for (int kk = 0; kk < 2; ++kk) {
      int cb = kk * 64 + g * 16;
      aq[kk] = *(const bfx8*)((const char*)Qs + row * 128 + (cb ^ ((row & 7) << 4)));
    }
  }

  float mrun = -1e30f, lrun = 0.f;   // stats for q-row w*16+ql (lane-local)
  fx4 acc[4];
#pragma unroll
  for (int d = 0; d < 4; ++d) acc[d] = {0.f, 0.f, 0.f, 0.f};

  const size_t kbase  = ((size_t)(b * S_)) * D_ + h * DH_;
  const size_t vtbase = (size_t)bh * DH_ * S_;
  char* pw = (char*)Ps + w * 2048;

  for (int kv0 = 0; kv0 < S_; kv0 += 64) {
    __syncthreads();
    {                                 // K,V tiles: 8 KB each, 1 gload/thread
      int o   = tid * 16;
      int row = o >> 7, cb = o & 127;
      int cbs = cb ^ ((row & 7) << 4);
      gload_lds16((const char*)Kb + (kbase + (size_t)(kv0 + row) * D_) * 2 + cbs,
                  (char*)Ks + o);
      gload_lds16((const char*)Vt + (vtbase + (size_t)row * S_ + kv0) * 2 + cbs,
                  (char*)Vs + o);
    }
    __syncthreads();

    // swapped QK^T: sc[nf] lane holds S[kv = nf*16+g*4+r][q = w*16+ql]
    fx4 sc[4];
#pragma unroll
    for (int nf = 0; nf < 4; ++nf) sc[nf] = {0.f, 0.f, 0.f, 0.f};
#pragma unroll
    for (int kk = 0; kk < 2; ++kk) {
      const int cb = kk * 64 + g * 16;
      bfx8 bk[4];
#pragma unroll
      for (int nf = 0; nf < 4; ++nf) {
        int row = nf * 16 + ql;
        bk[nf] = *(const bfx8*)((const char*)Ks + row * 128 + (cb ^ ((row & 7) << 4)));
      }
#pragma unroll
      for (int nf = 0; nf < 4; ++nf)
        sc[nf] = __builtin_amdgcn_mfma_f32_16x16x32_bf16(bk[nf], aq[kk], sc[nf], 0, 0, 0);
    }

    // scale + mask (kv = kv0 + nf*16 + g*4 + r)
    float sv[4][4];
#pragma unroll
    for (int nf = 0; nf < 4; ++nf) {
      float4 mk = *(const float4*)(mask + b * S_ + kv0 + nf * 16 + g * 4);
      sv[nf][0] = sc[nf][0] * 0.125f + mk.x;
      sv[nf][1] = sc[nf][1] * 0.125f + mk.y;
      sv[nf][2] = sc[nf][2] * 0.125f + mk.z;
      sv[nf][3] = sc[nf][3] * 0.125f + mk.w;
    }
    // row max/sum for q-row w*16+ql: 16 in-lane values + 2 shuffles
    float mx = sv[0][0];
#pragma unroll
    for (int nf = 0; nf < 4; ++nf)
#pragma unroll
      for (int r = 0; r < 4; ++r) mx = fmaxf(mx, sv[nf][r]);
    mx = fmaxf(mx, __shfl_xor(mx, 16));
    mx = fmaxf(mx, __shfl_xor(mx, 32));
    float mnew  = fmaxf(mrun, mx);
    float alpha = __expf(mrun - mnew);
    float rs = 0.f;
#pragma unroll
    for (int nf = 0; nf < 4; ++nf)
#pragma unroll
      for (int r = 0; r < 4; ++r) {
        float p = __expf(sv[nf][r] - mnew);
        sv[nf][r] = p; rs += p;
      }
    rs += __shfl_xor(rs, 16);
    rs += __shfl_xor(rs, 32);
    lrun = lrun * alpha + rs;
    mrun = mnew;

    // write P strip row ql (vector bfx4): elements kv = nf*16+g*4..+3
#pragma unroll
    for (int nf = 0; nf < 4; ++nf) {
      bfx4 pv;
      pv[0] = (__bf16)sv[nf][0]; pv[1] = (__bf16)sv[nf][1];
      pv[2] = (__bf16)sv[nf][2]; pv[3] = (__bf16)sv[nf][3];
      int c = (nf * 32 + g * 8) ^ ((ql & 7) << 4);
      *(bfx4*)(pw + ql * 128 + c) = pv;
    }

    // rescale acc: acc q-row g*4+r needs alpha held in lane g*4+r
    float af[4];
#pragma unroll
    for (int r = 0; r < 4; ++r) af[r] = __shfl(alpha, g * 4 + r);
#pragma unroll
    for (int d = 0; d < 4; ++d)
#pragma unroll
      for (int r = 0; r < 4; ++r) acc[d][r] *= af[r];

    // fence: P-strip writes complete + no compiler motion of PV reads above
    asm volatile("s_waitcnt lgkmcnt(0)" ::: "memory");
    __builtin_amdgcn_sched_barrier(0);

    // PV: A = P strip [16 q][64 kv], B = V via Vs rows
#pragma unroll
    for (int kk = 0; kk < 2; ++kk) {
      int prow = ql;
      int cb   = kk * 64 + g * 16;
      bfx8 ap  = *(const bfx8*)((const char*)pw + prow * 128 + (cb ^ ((prow & 7) << 4)));
#pragma unroll
      for (int d = 0; d < 4; ++d) {
        int vrow = d * 16 + ql;
        bfx8 bv  = *(const bfx8*)((const char*)Vs + vrow * 128 + (cb ^ ((vrow & 7) << 4)));
        acc[d] = __builtin_amdgcn_mfma_f32_16x16x32_bf16(ap, bv, acc[d], 0, 0, 0);
      }
    }
  }

  // finalize: acc q-row g*4+r, col dh = d*16+ql
  float linv = 1.0f / lrun;
#pragma unroll
  for (int r = 0; r < 4; ++r) {
    float inv = __shfl(linv, g * 4 + r);
    int qrow = q0 + w * 16 + g * 4 + r;
    size_t base = ((size_t)(b * S_) + qrow) * D_ + h * DH_;
#pragma unroll
    for (int d = 0; d < 4; ++d)
      ctx[base + d * 16 + ql] = (__bf16)(acc[d][r] * inv);
  }
}

// -------------------------------------------- residual + LayerNorm (row=1024)
template<bool WRITE_BF16>
__global__ __launch_bounds__(256)
void ln_kernel(const float* __restrict__ a, const float* __restrict__ b,
               const float* __restrict__ g, const float* __restrict__ beta,
               float* __restrict__ outf, __bf16* __restrict__ outb) {
  const int row = blockIdx.x;
  const int tid = threadIdx.x;
  const size_t base = (size_t)row * D_;
  float4 xa = *(const float4*)(a + base + tid * 4);
  float4 xb = *(const float4*)(b + base + tid * 4);
  float x[4] = {xa.x + xb.x, xa.y + xb.y, xa.z + xb.z, xa.w + xb.w};
  float s = x[0] + x[1] + x[2] + x[3];
#pragma unroll
  for (int m = 1; m < 64; m <<= 1) s += __shfl_xor(s, m);
  __shared__ float red[8];
  if ((tid & 63) == 0) red[tid >> 6] = s;
  __syncthreads();
  float mu = (red[0] + red[1] + red[2] + red[3]) * (1.0f / D_);
  float v0 = 0.f;
#pragma unroll
  for (int i = 0; i < 4; ++i) { float d = x[i] - mu; v0 += d * d; }
#pragma unroll
  for (int m = 1; m < 64; m <<= 1) v0 += __shfl_xor(v0, m);
  if ((tid & 63) == 0) red[4 + (tid >> 6)] = v0;
  __syncthreads();
  float var = (red[4] + red[5] + red[6] + red[7]) * (1.0f / D_);
  float rs = rsqrtf(var + 1e-12f);
#pragma unroll
  for (int i = 0; i < 4; ++i) {
    int col = tid * 4 + i;
    x[i] = (x[i] - mu) * rs * g[col] + beta[col];
  }
  *(float4*)(outf + base + tid * 4) = make_float4(x[0], x[1], x[2], x[3]);
  if (WRITE_BF16) {
    bfx4 o;
    o[0] = (__bf16)x[0]; o[1] = (__bf16)x[1]; o[2] = (__bf16)x[2]; o[3] = (__bf16)x[3];
    *(bfx4*)(outb + base + tid * 4) = o;
  }
}

// ---------------------------------------------------------------- launch
extern "C" void kernel_launch(void* const* d_in, const int* in_sizes, int n_in,
                              void* d_out, int out_size, void* d_ws, size_t ws_size,
                              hipStream_t stream) {
  const float* query    = (const float*)d_in[0];
  const float* key_in   = (const float*)d_in[1];
  const float* value_in = (const float*)d_in[2];
  const float* mask     = (const float*)d_in[3];
  const float* Wq = (const float*)d_in[4];  const float* bq = (const float*)d_in[5];
  const float* Wk = (const float*)d_in[6];  const float* bk = (const float*)d_in[7];
  const float* Wv = (const float*)d_in[8];  const float* bv = (const float*)d_in[9];
  const float* Wo = (const float*)d_in[10]; const float* bo = (const float*)d_in[11];
  const float* ln1g = (const float*)d_in[12]; const float* ln1b = (const float*)d_in[13];
  const float* Wi = (const float*)d_in[14]; const float* bi = (const float*)d_in[15];
  const float* Wd = (const float*)d_in[16]; const float* bd = (const float*)d_in[17];
  const float* ln2g = (const float*)d_in[18]; const float* ln2b = (const float*)d_in[19];

  char* ws = (char*)d_ws;
  const size_t MB = 1ull << 20;
  if (ws_size < 112 * MB) return;

  __bf16* xq   = (__bf16*)(ws + 0 * MB);
  __bf16* xk   = (__bf16*)(ws + 8 * MB);
  __bf16* xv   = (__bf16*)(ws + 16 * MB);
  float*  alin = (float*)(ws + 0 * MB);
  __bf16* x1b  = (__bf16*)(ws + 16 * MB);
  __bf16* qb   = (__bf16*)(ws + 24 * MB);
  __bf16* kb   = (__bf16*)(ws + 32 * MB);
  __bf16* vb   = (__bf16*)(ws + 40 * MB);
  __bf16* vt   = (__bf16*)(ws + 48 * MB);
  __bf16* inter= (__bf16*)(ws + 24 * MB);
  __bf16* ctxb = (__bf16*)(ws + 56 * MB);
  float*  ff   = (float*)(ws + 56 * MB);
  float*  x1f  = (float*)(ws + 72 * MB);
  __bf16* wqt  = (__bf16*)(ws + 88 * MB);
  __bf16* wkt  = (__bf16*)(ws + 90 * MB);
  __bf16* wvt  = (__bf16*)(ws + 92 * MB);
  __bf16* wot  = (__bf16*)(ws + 94 * MB);
  __bf16* wit  = (__bf16*)(ws + 96 * MB);
  __bf16* wdt  = (__bf16*)(ws + 104 * MB);

  dim3 b256(256);
  dim3 tblk(32, 8);
  const int n1 = M_ * D_;

  to_bf16_kernel<<<dim3(n1 / 1024), b256, 0, stream>>>(query, xq, n1);
  to_bf16_kernel<<<dim3(n1 / 1024), b256, 0, stream>>>(key_in, xk, n1);
  to_bf16_kernel<<<dim3(n1 / 1024), b256, 0, stream>>>(value_in, xv, n1);

  transpose_conv_kernel<<<dim3(D_ / 32, D_ / 32), tblk, 0, stream>>>(Wq, wqt, D_, D_);
  transpose_conv_kernel<<<dim3(D_ / 32, D_ / 32), tblk, 0, stream>>>(Wk, wkt, D_, D_);
  transpose_conv_kernel<<<dim3(D_ / 32, D_ / 32), tblk, 0, stream>>>(Wv, wvt, D_, D_);
  transpose_conv_kernel<<<dim3(D_ / 32, D_ / 32), tblk, 0, stream>>>(Wo, wot, D_, D_);
  transpose_conv_kernel<<<dim3(DFF_ / 32, D_ / 32), tblk, 0, stream>>>(Wi, wit, D_, DFF_);
  transpose_conv_kernel<<<dim3(D_ / 32, DFF_ / 32), tblk, 0, stream>>>(Wd, wdt, DFF_, D_);

  QKVArgs qa;
  qa.A[0] = xq;  qa.A[1] = xk;  qa.A[2] = xv;
  qa.Bt[0] = wqt; qa.Bt[1] = wkt; qa.Bt[2] = wvt;
  qa.bias[0] = bq; qa.bias[1] = bk; qa.bias[2] = bv;
  qa.out[0] = qb; qa.out[1] = kb; qa.out[2] = vb;
  qkv_gemm_kernel<<<dim3(D_ / 128, M_ / 128, 3), b256, 0, stream>>>(qa, D_, D_);

  transpose_v_kernel<<<dim3(S_ / 32, 2, B_ * H_), tblk, 0, stream>>>(vb, vt);

  attn_kernel<<<dim3(S_ / 128, B_ * H_), dim3(512), 0, stream>>>(qb, kb, vt, mask, ctxb);

  gemm_kernel<1, 64><<<dim3(D_ / 64, M_ / 128), b256, 0, stream>>>(ctxb, wot, bo, (void*)alin, D_, D_);

  ln_kernel<true><<<dim3(M_), b256, 0, stream>>>(alin, query, ln1g, ln1b, x1f, x1b);

  gemm_kernel<2, 128><<<dim3(DFF_ / 128, M_ / 128), b256, 0, stream>>>(x1b, wit, bi, (void*)inter, DFF_, D_);

  gemm_kernel<1, 64><<<dim3(D_ / 64, M_ / 128), b256, 0, stream>>>(inter, wdt, bd, (void*)ff, D_, DFF_);

  ln_kernel<false><<<dim3(M_), b256, 0, stream>>>(ff, x1f, ln2g, ln2b, (float*)d_out, nullptr);
}

// Round 8
// 306.497 us; speedup vs baseline: 1.0325x; 1.0325x over previous
//
#include <hip/hip_runtime.h>
#include <hip/hip_bf16.h>
#include <cmath>

#define B_   2
#define S_   2048
#define D_   1024
#define H_   16
#define DFF_ 4096
#define DH_  64
#define M_   (B_*S_)   // 4096 rows

typedef __bf16 bfx8 __attribute__((ext_vector_type(8)));
typedef __bf16 bfx4 __attribute__((ext_vector_type(4)));
typedef float  fx4  __attribute__((ext_vector_type(4)));

// ---------------------------------------------------------------- utilities
__device__ __forceinline__ void gload_lds16(const void* g, void* l) {
  __builtin_amdgcn_global_load_lds((__attribute__((address_space(1))) void*)(g),
                                   (__attribute__((address_space(3))) void*)(l),
                                   16, 0, 0);
}

// ------------------------------------------------------------- fp32 -> bf16
__global__ __launch_bounds__(256)
void to_bf16_kernel(const float* __restrict__ in, __bf16* __restrict__ out, int n) {
  int i = (blockIdx.x * 256 + threadIdx.x) * 4;
  if (i < n) {
    float4 v = *(const float4*)(in + i);
    bfx4 o;
    o[0] = (__bf16)v.x; o[1] = (__bf16)v.y; o[2] = (__bf16)v.z; o[3] = (__bf16)v.w;
    *(bfx4*)(out + i) = o;
  }
}

// --------------------------------------- W [R][C] f32 -> Wt [C][R] bf16
__global__ __launch_bounds__(256)
void transpose_conv_kernel(const float* __restrict__ in, __bf16* __restrict__ out,
                           int R, int C) {
  __shared__ float t[32][33];
  int r0 = blockIdx.y * 32, c0 = blockIdx.x * 32;
  int tx = threadIdx.x, ty = threadIdx.y;   // 32 x 8
#pragma unroll
  for (int j = 0; j < 4; ++j) {
    int r = ty + j * 8;
    t[r][tx] = in[(size_t)(r0 + r) * C + c0 + tx];
  }
  __syncthreads();
#pragma unroll
  for (int j = 0; j < 4; ++j) {
    int c = ty + j * 8;
    out[(size_t)(c0 + c) * R + r0 + tx] = (__bf16)t[tx][c];
  }
}

// ----------------------- V [B,S,H,DH] bf16 -> Vt [B,H,DH,S] bf16
__global__ __launch_bounds__(256)
void transpose_v_kernel(const __bf16* __restrict__ vb, __bf16* __restrict__ vt) {
  __shared__ __bf16 t[32][33];
  int bh = blockIdx.z;
  int b = bh >> 4, h = bh & 15;
  int s0 = blockIdx.x * 32, d0 = blockIdx.y * 32;
  int tx = threadIdx.x, ty = threadIdx.y;
#pragma unroll
  for (int j = 0; j < 4; ++j) {
    int s = ty + j * 8;
    t[s][tx] = vb[(size_t)((b * S_ + s0 + s) * H_ + h) * DH_ + d0 + tx];
  }
  __syncthreads();
#pragma unroll
  for (int j = 0; j < 4; ++j) {
    int d = ty + j * 8;
    vt[(size_t)(bh * DH_ + d0 + d) * S_ + s0 + tx] = t[tx][d];
  }
}

// --------------------------------------------------------------- GEMM core
// C[m][n] = sum_k A[m][k]*B[k][n] + bias[n].  A:[M][K] bf16, Bt:[N][K] bf16.
// MODE 0: bf16 out. 1: f32 out. 2: exact-GELU bf16 out.
// Block tile: 128 x TBN, BK=64, 256 threads (4 waves as 2x2).
template<int MODE, int TBN>
__device__ __forceinline__ void gemm_body(const __bf16* __restrict__ A,
                                          const __bf16* __restrict__ Bt,
                                          const float* __restrict__ bias,
                                          void* __restrict__ out,
                                          int Ndim, int Kdim,
                                          int m0, int n0,
                                          __bf16* As, __bf16* Bs) {
  const int tid  = threadIdx.x;
  const int lane = tid & 63;
  const int w    = tid >> 6;
  const int wm   = w >> 1, wn = w & 1;
  constexpr int NF = TBN / 32;          // N-fragments per wave

  fx4 acc[4][NF];
#pragma unroll
  for (int i = 0; i < 4; ++i)
#pragma unroll
    for (int j = 0; j < NF; ++j) acc[i][j] = {0.f, 0.f, 0.f, 0.f};

  const int KT = Kdim / 64;
  for (int kt = 0; kt < KT; ++kt) {
    __syncthreads();
    const int kb0 = kt * 64;
#pragma unroll
    for (int i = 0; i < 4; ++i) {            // A tile: 16 KB
      int o   = tid * 16 + i * 4096;
      int row = o >> 7, cb = o & 127;
      int cbs = cb ^ ((row & 7) << 4);
      gload_lds16((const char*)A + ((size_t)(m0 + row) * Kdim + kb0) * 2 + cbs,
                  (char*)As + o);
    }
#pragma unroll
    for (int i = 0; i < TBN / 32; ++i) {     // B tile: TBN*128 bytes
      int o   = tid * 16 + i * 4096;
      int row = o >> 7, cb = o & 127;
      int cbs = cb ^ ((row & 7) << 4);
      gload_lds16((const char*)Bt + ((size_t)(n0 + row) * Kdim + kb0) * 2 + cbs,
                  (char*)Bs + o);
    }
    __syncthreads();

#pragma unroll
    for (int kk = 0; kk < 2; ++kk) {
      bfx8 afr[4], bfr[NF];
      const int cb = kk * 64 + ((lane >> 4) << 4);
#pragma unroll
      for (int mf = 0; mf < 4; ++mf) {
        int row = wm * 64 + mf * 16 + (lane & 15);
        afr[mf] = *(const bfx8*)((const char*)As + row * 128 + (cb ^ ((row & 7) << 4)));
      }
#pragma unroll
      for (int nf = 0; nf < NF; ++nf) {
        int row = wn * (TBN / 2) + nf * 16 + (lane & 15);
        bfr[nf] = *(const bfx8*)((const char*)Bs + row * 128 + (cb ^ ((row & 7) << 4)));
      }
#pragma unroll
      for (int mf = 0; mf < 4; ++mf)
#pragma unroll
        for (int nf = 0; nf < NF; ++nf)
          acc[mf][nf] = __builtin_amdgcn_mfma_f32_16x16x32_bf16(afr[mf], bfr[nf],
                                                                acc[mf][nf], 0, 0, 0);
    }
  }

#pragma unroll
  for (int mf = 0; mf < 4; ++mf) {
#pragma unroll
    for (int nf = 0; nf < NF; ++nf) {
      int col = n0 + wn * (TBN / 2) + nf * 16 + (lane & 15);
      float bvl = bias[col];
#pragma unroll
      for (int r = 0; r < 4; ++r) {
        int rowg = m0 + wm * 64 + mf * 16 + ((lane >> 4) << 2) + r;
        float v = acc[mf][nf][r] + bvl;
        if (MODE == 2) v = 0.5f * v * (1.0f + erff(v * 0.70710678118654752f));
        if (MODE == 1) ((float*)out)[(size_t)rowg * Ndim + col] = v;
        else          ((__bf16*)out)[(size_t)rowg * Ndim + col] = (__bf16)v;
      }
    }
  }
}

template<int MODE, int TBN>
__global__ __launch_bounds__(256)
void gemm_kernel(const __bf16* __restrict__ A, const __bf16* __restrict__ Bt,
                 const float* __restrict__ bias, void* __restrict__ out,
                 int Ndim, int Kdim) {
  __shared__ alignas(16) __bf16 As[128 * 64];
  __shared__ alignas(16) __bf16 Bs[TBN * 64];
  gemm_body<MODE, TBN>(A, Bt, bias, out, Ndim, Kdim,
                       blockIdx.y * 128, blockIdx.x * TBN, As, Bs);
}

struct QKVArgs {
  const __bf16* A[3]; const __bf16* Bt[3]; const float* bias[3]; __bf16* out[3];
};

// fused QKV: blockIdx.z selects projection -> 768 blocks (3/CU)
__global__ __launch_bounds__(256)
void qkv_gemm_kernel(QKVArgs args, int Ndim, int Kdim) {
  __shared__ alignas(16) __bf16 As[128 * 64];
  __shared__ alignas(16) __bf16 Bs[128 * 64];
  int z = blockIdx.z;
  gemm_body<0, 128>(args.A[z], args.Bt[z], args.bias[z], (void*)args.out[z],
                    Ndim, Kdim, blockIdx.y * 128, blockIdx.x * 128, As, Bs);
}

// --------------------------------------------------------- flash attention
// Round-7 validated body (swapped QK^T, fenced P path) + THIS ROUND's delta:
// double-buffered K/V staging with counted vmcnt (T3/T4-lite). Per iter:
// issue next tile's gload_lds into buf^1, s_waitcnt vmcnt(2) (next stays in
// flight), raw s_barrier, compute buf[t&1], raw end barrier (no drain).
// sched_barrier(0) pins compiler motion around the counted window (rule #18).
__global__ __launch_bounds__(512)
void attn_kernel(const __bf16* __restrict__ Qb, const __bf16* __restrict__ Kb,
                 const __bf16* __restrict__ Vt, const float* __restrict__ mask,
                 __bf16* __restrict__ ctx) {
  __shared__ alignas(16) __bf16 Qs[128 * 64];        // 16 KB
  __shared__ alignas(16) __bf16 Ks[2 * 64 * 64];     // 16 KB (dbuf)
  __shared__ alignas(16) __bf16 Vs[2 * 64 * 64];     // 16 KB (dbuf)
  __shared__ alignas(16) __bf16 Ps[8 * 16 * 64];     // 16 KB per-wave strips

  const int tid  = threadIdx.x;
  const int lane = tid & 63;
  const int w    = tid >> 6;          // 0..7
  const int g    = lane >> 4;         // 0..3
  const int ql   = lane & 15;
  const int bh   = blockIdx.y;
  const int b    = bh >> 4;
  const int h    = bh & 15;
  const int q0   = blockIdx.x * 128;

  const size_t kbase  = ((size_t)(b * S_)) * D_ + h * DH_;
  const size_t vtbase = (size_t)bh * DH_ * S_;

  // stage Q tile (16 KB) + kv tile 0 into buf 0
  const size_t qbase = ((size_t)(b * S_) + q0) * D_ + h * DH_;
#pragma unroll
  for (int i = 0; i < 2; ++i) {
    int o   = tid * 16 + i * 8192;
    int row = o >> 7, cb = o & 127;
    int cbs = cb ^ ((row & 7) << 4);
    gload_lds16((const char*)Qb + (qbase + (size_t)row * D_) * 2 + cbs, (char*)Qs + o);
  }
  {
    int o   = tid * 16;
    int row = o >> 7, cb = o & 127;
    int cbs = cb ^ ((row & 7) << 4);
    gload_lds16((const char*)Kb + (kbase + (size_t)row * D_) * 2 + cbs, (char*)Ks + o);
    gload_lds16((const char*)Vt + (vtbase + (size_t)row * S_) * 2 + cbs, (char*)Vs + o);
  }
  __syncthreads();   // full drain: Q + tile0 landed

  bfx8 aq[2];   // Q fragment: row w*16+ql, k-halves
  {
    int row = w * 16 + ql;
#pragma unroll
    for (int kk = 0; kk < 2; ++kk) {
      int cb = kk * 64 + g * 16;
      aq[kk] = *(const bfx8*)((const char*)Qs + row * 128 + (cb ^ ((row & 7) << 4)));
    }
  }

  float mrun = -1e30f, lrun = 0.f;   // stats for q-row w*16+ql (lane-local)
  fx4 acc[4];
#pragma unroll
  for (int d = 0; d < 4; ++d) acc[d] = {0.f, 0.f, 0.f, 0.f};

  char* pw = (char*)Ps + w * 2048;
  const int NT = S_ / 64;            // 32 kv tiles

  for (int t = 0; t < NT; ++t) {
    const int kv0 = t * 64;
    // issue next tile's loads into buf^1 (stay in flight across the barrier)
    if (t < NT - 1) {
      int o   = tid * 16;
      int row = o >> 7, cb = o & 127;
      int cbs = cb ^ ((row & 7) << 4);
      int nkv = kv0 + 64;
      gload_lds16((const char*)Kb + (kbase + (size_t)(nkv + row) * D_) * 2 + cbs,
                  (char*)Ks + ((t + 1) & 1) * 8192 + o);
      gload_lds16((const char*)Vt + (vtbase + (size_t)row * S_ + nkv) * 2 + cbs,
                  (char*)Vs + ((t + 1) & 1) * 8192 + o);
    }
    __builtin_amdgcn_sched_barrier(0);
    if (t > 0) {     // tile 0 was drained in prologue
      if (t < NT - 1) asm volatile("s_waitcnt vmcnt(2)" ::: "memory");
      else            asm volatile("s_waitcnt vmcnt(0)" ::: "memory");
      __builtin_amdgcn_s_barrier();            // all waves: current tile landed
      __builtin_amdgcn_sched_barrier(0);       // no load hoists above this
    }
    const char* Kc = (const char*)Ks + (t & 1) * 8192;
    const char* Vc = (const char*)Vs + (t & 1) * 8192;

    // swapped QK^T: sc[nf] lane holds S[kv = nf*16+g*4+r][q = w*16+ql]
    fx4 sc[4];
#pragma unroll
    for (int nf = 0; nf < 4; ++nf) sc[nf] = {0.f, 0.f, 0.f, 0.f};
#pragma unroll
    for (int kk = 0; kk < 2; ++kk) {
      const int cb = kk * 64 + g * 16;
      bfx8 bk[4];
#pragma unroll
      for (int nf = 0; nf < 4; ++nf) {
        int row = nf * 16 + ql;
        bk[nf] = *(const bfx8*)(Kc + row * 128 + (cb ^ ((row & 7) << 4)));
      }
#pragma unroll
      for (int nf = 0; nf < 4; ++nf)
        sc[nf] = __builtin_amdgcn_mfma_f32_16x16x32_bf16(bk[nf], aq[kk], sc[nf], 0, 0, 0);
    }

    // scale + mask (kv = kv0 + nf*16 + g*4 + r)
    float sv[4][4];
#pragma unroll
    for (int nf = 0; nf < 4; ++nf) {
      float4 mk = *(const float4*)(mask + b * S_ + kv0 + nf * 16 + g * 4);
      sv[nf][0] = sc[nf][0] * 0.125f + mk.x;
      sv[nf][1] = sc[nf][1] * 0.125f + mk.y;
      sv[nf][2] = sc[nf][2] * 0.125f + mk.z;
      sv[nf][3] = sc[nf][3] * 0.125f + mk.w;
    }
    // row max/sum for q-row w*16+ql: 16 in-lane values + 2 shuffles
    float mx = sv[0][0];
#pragma unroll
    for (int nf = 0; nf < 4; ++nf)
#pragma unroll
      for (int r = 0; r < 4; ++r) mx = fmaxf(mx, sv[nf][r]);
    mx = fmaxf(mx, __shfl_xor(mx, 16));
    mx = fmaxf(mx, __shfl_xor(mx, 32));
    float mnew  = fmaxf(mrun, mx);
    float alpha = __expf(mrun - mnew);
    float rs = 0.f;
#pragma unroll
    for (int nf = 0; nf < 4; ++nf)
#pragma unroll
      for (int r = 0; r < 4; ++r) {
        float p = __expf(sv[nf][r] - mnew);
        sv[nf][r] = p; rs += p;
      }
    rs += __shfl_xor(rs, 16);
    rs += __shfl_xor(rs, 32);
    lrun = lrun * alpha + rs;
    mrun = mnew;

    // write P strip row ql (vector bfx4): elements kv = nf*16+g*4..+3
#pragma unroll
    for (int nf = 0; nf < 4; ++nf) {
      bfx4 pv;
      pv[0] = (__bf16)sv[nf][0]; pv[1] = (__bf16)sv[nf][1];
      pv[2] = (__bf16)sv[nf][2]; pv[3] = (__bf16)sv[nf][3];
      int c = (nf * 32 + g * 8) ^ ((ql & 7) << 4);
      *(bfx4*)(pw + ql * 128 + c) = pv;
    }

    // rescale acc: acc q-row g*4+r needs alpha held in lane g*4+r
    float af[4];
#pragma unroll
    for (int r = 0; r < 4; ++r) af[r] = __shfl(alpha, g * 4 + r);
#pragma unroll
    for (int d = 0; d < 4; ++d)
#pragma unroll
      for (int r = 0; r < 4; ++r) acc[d][r] *= af[r];

    // fence: P-strip writes complete + no compiler motion of PV reads above
    asm volatile("s_waitcnt lgkmcnt(0)" ::: "memory");
    __builtin_amdgcn_sched_barrier(0);

    // PV: A = P strip [16 q][64 kv], B = V via Vc rows
#pragma unroll
    for (int kk = 0; kk < 2; ++kk) {
      int prow = ql;
      int cb   = kk * 64 + g * 16;
      bfx8 ap  = *(const bfx8*)((const char*)pw + prow * 128 + (cb ^ ((prow & 7) << 4)));
#pragma unroll
      for (int d = 0; d < 4; ++d) {
        int vrow = d * 16 + ql;
        bfx8 bv  = *(const bfx8*)(Vc + vrow * 128 + (cb ^ ((vrow & 7) << 4)));
        acc[d] = __builtin_amdgcn_mfma_f32_16x16x32_bf16(ap, bv, acc[d], 0, 0, 0);
      }
    }

    // end barrier (raw, NO drain): all waves done reading buf[t&1] before
    // it is overwritten by tile t+2's staging next iteration.
    __builtin_amdgcn_s_barrier();
    __builtin_amdgcn_sched_barrier(0);
  }

  // finalize: acc q-row g*4+r, col dh = d*16+ql
  float linv = 1.0f / lrun;
#pragma unroll
  for (int r = 0; r < 4; ++r) {
    float inv = __shfl(linv, g * 4 + r);
    int qrow = q0 + w * 16 + g * 4 + r;
    size_t base = ((size_t)(b * S_) + qrow) * D_ + h * DH_;
#pragma unroll
    for (int d = 0; d < 4; ++d)
      ctx[base + d * 16 + ql] = (__bf16)(acc[d][r] * inv);
  }
}

// -------------------------------------------- residual + LayerNorm (row=1024)
template<bool WRITE_BF16>
__global__ __launch_bounds__(256)
void ln_kernel(const float* __restrict__ a, const float* __restrict__ b,
               const float* __restrict__ g, const float* __restrict__ beta,
               float* __restrict__ outf, __bf16* __restrict__ outb) {
  const int row = blockIdx.x;
  const int tid = threadIdx.x;
  const size_t base = (size_t)row * D_;
  float4 xa = *(const float4*)(a + base + tid * 4);
  float4 xb = *(const float4*)(b + base + tid * 4);
  float x[4] = {xa.x + xb.x, xa.y + xb.y, xa.z + xb.z, xa.w + xb.w};
  float s = x[0] + x[1] + x[2] + x[3];
#pragma unroll
  for (int m = 1; m < 64; m <<= 1) s += __shfl_xor(s, m);
  __shared__ float red[8];
  if ((tid & 63) == 0) red[tid >> 6] = s;
  __syncthreads();
  float mu = (red[0] + red[1] + red[2] + red[3]) * (1.0f / D_);
  float v0 = 0.f;
#pragma unroll
  for (int i = 0; i < 4; ++i) { float d = x[i] - mu; v0 += d * d; }
#pragma unroll
  for (int m = 1; m < 64; m <<= 1) v0 += __shfl_xor(v0, m);
  if ((tid & 63) == 0) red[4 + (tid >> 6)] = v0;
  __syncthreads();
  float var = (red[4] + red[5] + red[6] + red[7]) * (1.0f / D_);
  float rs = rsqrtf(var + 1e-12f);
#pragma unroll
  for (int i = 0; i < 4; ++i) {
    int col = tid * 4 + i;
    x[i] = (x[i] - mu) * rs * g[col] + beta[col];
  }
  *(float4*)(outf + base + tid * 4) = make_float4(x[0], x[1], x[2], x[3]);
  if (WRITE_BF16) {
    bfx4 o;
    o[0] = (__bf16)x[0]; o[1] = (__bf16)x[1]; o[2] = (__bf16)x[2]; o[3] = (__bf16)x[3];
    *(bfx4*)(outb + base + tid * 4) = o;
  }
}

// ---------------------------------------------------------------- launch
extern "C" void kernel_launch(void* const* d_in, const int* in_sizes, int n_in,
                              void* d_out, int out_size, void* d_ws, size_t ws_size,
                              hipStream_t stream) {
  const float* query    = (const float*)d_in[0];
  const float* key_in   = (const float*)d_in[1];
  const float* value_in = (const float*)d_in[2];
  const float* mask     = (const float*)d_in[3];
  const float* Wq = (const float*)d_in[4];  const float* bq = (const float*)d_in[5];
  const float* Wk = (const float*)d_in[6];  const float* bk = (const float*)d_in[7];
  const float* Wv = (const float*)d_in[8];  const float* bv = (const float*)d_in[9];
  const float* Wo = (const float*)d_in[10]; const float* bo = (const float*)d_in[11];
  const float* ln1g = (const float*)d_in[12]; const float* ln1b = (const float*)d_in[13];
  const float* Wi = (const float*)d_in[14]; const float* bi = (const float*)d_in[15];
  const float* Wd = (const float*)d_in[16]; const float* bd = (const float*)d_in[17];
  const float* ln2g = (const float*)d_in[18]; const float* ln2b = (const float*)d_in[19];

  char* ws = (char*)d_ws;
  const size_t MB = 1ull << 20;
  if (ws_size < 112 * MB) return;

  __bf16* xq   = (__bf16*)(ws + 0 * MB);
  __bf16* xk   = (__bf16*)(ws + 8 * MB);
  __bf16* xv   = (__bf16*)(ws + 16 * MB);
  float*  alin = (float*)(ws + 0 * MB);
  __bf16* x1b  = (__bf16*)(ws + 16 * MB);
  __bf16* qb   = (__bf16*)(ws + 24 * MB);
  __bf16* kb   = (__bf16*)(ws + 32 * MB);
  __bf16* vb   = (__bf16*)(ws + 40 * MB);
  __bf16* vt   = (__bf16*)(ws + 48 * MB);
  __bf16* inter= (__bf16*)(ws + 24 * MB);
  __bf16* ctxb = (__bf16*)(ws + 56 * MB);
  float*  ff   = (float*)(ws + 56 * MB);
  float*  x1f  = (float*)(ws + 72 * MB);
  __bf16* wqt  = (__bf16*)(ws + 88 * MB);
  __bf16* wkt  = (__bf16*)(ws + 90 * MB);
  __bf16* wvt  = (__bf16*)(ws + 92 * MB);
  __bf16* wot  = (__bf16*)(ws + 94 * MB);
  __bf16* wit  = (__bf16*)(ws + 96 * MB);
  __bf16* wdt  = (__bf16*)(ws + 104 * MB);

  dim3 b256(256);
  dim3 tblk(32, 8);
  const int n1 = M_ * D_;

  to_bf16_kernel<<<dim3(n1 / 1024), b256, 0, stream>>>(query, xq, n1);
  to_bf16_kernel<<<dim3(n1 / 1024), b256, 0, stream>>>(key_in, xk, n1);
  to_bf16_kernel<<<dim3(n1 / 1024), b256, 0, stream>>>(value_in, xv, n1);

  transpose_conv_kernel<<<dim3(D_ / 32, D_ / 32), tblk, 0, stream>>>(Wq, wqt, D_, D_);
  transpose_conv_kernel<<<dim3(D_ / 32, D_ / 32), tblk, 0, stream>>>(Wk, wkt, D_, D_);
  transpose_conv_kernel<<<dim3(D_ / 32, D_ / 32), tblk, 0, stream>>>(Wv, wvt, D_, D_);
  transpose_conv_kernel<<<dim3(D_ / 32, D_ / 32), tblk, 0, stream>>>(Wo, wot, D_, D_);
  transpose_conv_kernel<<<dim3(DFF_ / 32, D_ / 32), tblk, 0, stream>>>(Wi, wit, D_, DFF_);
  transpose_conv_kernel<<<dim3(D_ / 32, DFF_ / 32), tblk, 0, stream>>>(Wd, wdt, DFF_, D_);

  QKVArgs qa;
  qa.A[0] = xq;  qa.A[1] = xk;  qa.A[2] = xv;
  qa.Bt[0] = wqt; qa.Bt[1] = wkt; qa.Bt[2] = wvt;
  qa.bias[0] = bq; qa.bias[1] = bk; qa.bias[2] = bv;
  qa.out[0] = qb; qa.out[1] = kb; qa.out[2] = vb;
  qkv_gemm_kernel<<<dim3(D_ / 128, M_ / 128, 3), b256, 0, stream>>>(qa, D_, D_);

  transpose_v_kernel<<<dim3(S_ / 32, 2, B_ * H_), tblk, 0, stream>>>(vb, vt);

  attn_kernel<<<dim3(S_ / 128, B_ * H_), dim3(512), 0, stream>>>(qb, kb, vt, mask, ctxb);

  gemm_kernel<1, 64><<<dim3(D_ / 64, M_ / 128), b256, 0, stream>>>(ctxb, wot, bo, (void*)alin, D_, D_);

  ln_kernel<true><<<dim3(M_), b256, 0, stream>>>(alin, query, ln1g, ln1b, x1f, x1b);

  gemm_kernel<2, 128><<<dim3(DFF_ / 128, M_ / 128), b256, 0, stream>>>(x1b, wit, bi, (void*)inter, DFF_, D_);

  gemm_kernel<1, 64><<<dim3(D_ / 64, M_ / 128), b256, 0, stream>>>(inter, wdt, bd, (void*)ff, D_, DFF_);

  ln_kernel<false><<<dim3(M_), b256, 0, stream>>>(ff, x1f, ln2g, ln2b, (float*)d_out, nullptr);
}

// Round 9
// 294.645 us; speedup vs baseline: 1.0741x; 1.0402x over previous
//
#include <hip/hip_runtime.h>
#include <hip/hip_bf16.h>
#include <cmath>

#define B_   2
#define S_   2048
#define D_   1024
#define H_   16
#define DFF_ 4096
#define DH_  64
#define M_   (B_*S_)   // 4096 rows

typedef __bf16 bfx8 __attribute__((ext_vector_type(8)));
typedef __bf16 bfx4 __attribute__((ext_vector_type(4)));
typedef float  fx4  __attribute__((ext_vector_type(4)));

// ---------------------------------------------------------------- utilities
__device__ __forceinline__ void gload_lds16(const void* g, void* l) {
  __builtin_amdgcn_global_load_lds((__attribute__((address_space(1))) void*)(g),
                                   (__attribute__((address_space(3))) void*)(l),
                                   16, 0, 0);
}

// ------------------------------------------------------------- fp32 -> bf16
__global__ __launch_bounds__(256)
void to_bf16_kernel(const float* __restrict__ in, __bf16* __restrict__ out, int n) {
  int i = (blockIdx.x * 256 + threadIdx.x) * 4;
  if (i < n) {
    float4 v = *(const float4*)(in + i);
    bfx4 o;
    o[0] = (__bf16)v.x; o[1] = (__bf16)v.y; o[2] = (__bf16)v.z; o[3] = (__bf16)v.w;
    *(bfx4*)(out + i) = o;
  }
}

// --------------------------------------- W [R][C] f32 -> Wt [C][R] bf16
__global__ __launch_bounds__(256)
void transpose_conv_kernel(const float* __restrict__ in, __bf16* __restrict__ out,
                           int R, int C) {
  __shared__ float t[32][33];
  int r0 = blockIdx.y * 32, c0 = blockIdx.x * 32;
  int tx = threadIdx.x, ty = threadIdx.y;   // 32 x 8
#pragma unroll
  for (int j = 0; j < 4; ++j) {
    int r = ty + j * 8;
    t[r][tx] = in[(size_t)(r0 + r) * C + c0 + tx];
  }
  __syncthreads();
#pragma unroll
  for (int j = 0; j < 4; ++j) {
    int c = ty + j * 8;
    out[(size_t)(c0 + c) * R + r0 + tx] = (__bf16)t[tx][c];
  }
}

// ----------------------- V [B,S,H,DH] bf16 -> Vt [B,H,DH,S] bf16
__global__ __launch_bounds__(256)
void transpose_v_kernel(const __bf16* __restrict__ vb, __bf16* __restrict__ vt) {
  __shared__ __bf16 t[32][33];
  int bh = blockIdx.z;
  int b = bh >> 4, h = bh & 15;
  int s0 = blockIdx.x * 32, d0 = blockIdx.y * 32;
  int tx = threadIdx.x, ty = threadIdx.y;
#pragma unroll
  for (int j = 0; j < 4; ++j) {
    int s = ty + j * 8;
    t[s][tx] = vb[(size_t)((b * S_ + s0 + s) * H_ + h) * DH_ + d0 + tx];
  }
  __syncthreads();
#pragma unroll
  for (int j = 0; j < 4; ++j) {
    int d = ty + j * 8;
    vt[(size_t)(bh * DH_ + d0 + d) * S_ + s0 + tx] = t[tx][d];
  }
}

// --------------------------------------------------------------- GEMM 128-tile
// (round-8 validated; used for Wo and Wd where 256-tile grids underfill)
template<int MODE, int TBN>
__device__ __forceinline__ void gemm_body(const __bf16* __restrict__ A,
                                          const __bf16* __restrict__ Bt,
                                          const float* __restrict__ bias,
                                          void* __restrict__ out,
                                          int Ndim, int Kdim,
                                          int m0, int n0,
                                          __bf16* As, __bf16* Bs) {
  const int tid  = threadIdx.x;
  const int lane = tid & 63;
  const int w    = tid >> 6;
  const int wm   = w >> 1, wn = w & 1;
  constexpr int NF = TBN / 32;

  fx4 acc[4][NF];
#pragma unroll
  for (int i = 0; i < 4; ++i)
#pragma unroll
    for (int j = 0; j < NF; ++j) acc[i][j] = {0.f, 0.f, 0.f, 0.f};

  const int KT = Kdim / 64;
  for (int kt = 0; kt < KT; ++kt) {
    __syncthreads();
    const int kb0 = kt * 64;
#pragma unroll
    for (int i = 0; i < 4; ++i) {
      int o   = tid * 16 + i * 4096;
      int row = o >> 7, cb = o & 127;
      int cbs = cb ^ ((row & 7) << 4);
      gload_lds16((const char*)A + ((size_t)(m0 + row) * Kdim + kb0) * 2 + cbs,
                  (char*)As + o);
    }
#pragma unroll
    for (int i = 0; i < TBN / 32; ++i) {
      int o   = tid * 16 + i * 4096;
      int row = o >> 7, cb = o & 127;
      int cbs = cb ^ ((row & 7) << 4);
      gload_lds16((const char*)Bt + ((size_t)(n0 + row) * Kdim + kb0) * 2 + cbs,
                  (char*)Bs + o);
    }
    __syncthreads();

#pragma unroll
    for (int kk = 0; kk < 2; ++kk) {
      bfx8 afr[4], bfr[NF];
      const int cb = kk * 64 + ((lane >> 4) << 4);
#pragma unroll
      for (int mf = 0; mf < 4; ++mf) {
        int row = wm * 64 + mf * 16 + (lane & 15);
        afr[mf] = *(const bfx8*)((const char*)As + row * 128 + (cb ^ ((row & 7) << 4)));
      }
#pragma unroll
      for (int nf = 0; nf < NF; ++nf) {
        int row = wn * (TBN / 2) + nf * 16 + (lane & 15);
        bfr[nf] = *(const bfx8*)((const char*)Bs + row * 128 + (cb ^ ((row & 7) << 4)));
      }
#pragma unroll
      for (int mf = 0; mf < 4; ++mf)
#pragma unroll
        for (int nf = 0; nf < NF; ++nf)
          acc[mf][nf] = __builtin_amdgcn_mfma_f32_16x16x32_bf16(afr[mf], bfr[nf],
                                                                acc[mf][nf], 0, 0, 0);
    }
  }

#pragma unroll
  for (int mf = 0; mf < 4; ++mf) {
#pragma unroll
    for (int nf = 0; nf < NF; ++nf) {
      int col = n0 + wn * (TBN / 2) + nf * 16 + (lane & 15);
      float bvl = bias[col];
#pragma unroll
      for (int r = 0; r < 4; ++r) {
        int rowg = m0 + wm * 64 + mf * 16 + ((lane >> 4) << 2) + r;
        float v = acc[mf][nf][r] + bvl;
        if (MODE == 2) v = 0.5f * v * (1.0f + erff(v * 0.70710678118654752f));
        if (MODE == 1) ((float*)out)[(size_t)rowg * Ndim + col] = v;
        else          ((__bf16*)out)[(size_t)rowg * Ndim + col] = (__bf16)v;
      }
    }
  }
}

template<int MODE, int TBN>
__global__ __launch_bounds__(256)
void gemm_kernel(const __bf16* __restrict__ A, const __bf16* __restrict__ Bt,
                 const float* __restrict__ bias, void* __restrict__ out,
                 int Ndim, int Kdim) {
  __shared__ alignas(16) __bf16 As[128 * 64];
  __shared__ alignas(16) __bf16 Bs[TBN * 64];
  gemm_body<MODE, TBN>(A, Bt, bias, out, Ndim, Kdim,
                       blockIdx.y * 128, blockIdx.x * TBN, As, Bs);
}

// --------------------------------------------------------------- GEMM 256-tile
// 8-phase schedule (guide T3+T4+T5). 512 thr = 8 waves (2M x 4N); per-wave
// C block 128x64 = acc[8][4]. LDS 128KB dynamic: A dbuf 2x32KB, B dbuf 2x32KB.
// K-tile t in buf t&1. Per tile, 4 phases p=(ah=p>>1, kk=p&1); per phase:
// stage 1 half-tile -> ds_read 8 frags -> barrier -> lgkm(0) -> 16 MFMA ->
// barrier. Stage queue per tile t: p0: A-h1(t+1); p1: B-h0(t+1); p2: B-h1(t+1);
// p3: A-h0(t+2). A halves INTERLEAVED (h0 = rows {0-63,128-191}) so the phase-p
// readers of each target region (ah==h rows for both wm) retire >=1 barrier
// before the stage issues. Boundary: vmcnt(2) (A-h0(t+2) stays in flight).
__device__ __forceinline__ void stage_a256(const __bf16* __restrict__ A, int m0,
                                           int Kdim, int tile, int h, char* Asm) {
  char* dst = Asm + (tile & 1) * 32768;
  const int kb0 = tile * 64;
  const int tid = threadIdx.x;
#pragma unroll
  for (int it = 0; it < 2; ++it) {
    int o = tid * 16 + it * 8192;
    int lrow = o >> 7, cb = o & 127;
    int r = (lrow & 63) + h * 64 + ((lrow >> 6) << 7);   // interleaved halves
    int csrc = cb ^ ((r & 7) << 4);
    gload_lds16((const char*)A + ((size_t)(m0 + r) * Kdim + kb0) * 2 + csrc,
                dst + r * 128 + cb);
  }
}
__device__ __forceinline__ void stage_b256(const __bf16* __restrict__ Bt, int n0,
                                           int Kdim, int tile, int h, char* Bsm) {
  char* dst = Bsm + (tile & 1) * 32768;
  const int kb0 = tile * 64;
  const int tid = threadIdx.x;
#pragma unroll
  for (int it = 0; it < 2; ++it) {
    int o = tid * 16 + it * 8192;
    int lrow = o >> 7, cb = o & 127;
    int r = h * 128 + lrow;                              // contiguous halves
    int csrc = cb ^ ((r & 7) << 4);
    gload_lds16((const char*)Bt + ((size_t)(n0 + r) * Kdim + kb0) * 2 + csrc,
                dst + r * 128 + cb);
  }
}

template<int MODE>
__device__ __forceinline__ void gemm256_body(const __bf16* __restrict__ A,
                                             const __bf16* __restrict__ Bt,
                                             const float* __restrict__ bias,
                                             void* __restrict__ out,
                                             int Ndim, int Kdim, int m0, int n0) {
  extern __shared__ char smem[];     // 128 KB
  char* Asm = smem;                  // A: 2 bufs x 32KB
  char* Bsm = smem + 65536;          // B: 2 bufs x 32KB
  const int tid  = threadIdx.x;
  const int lane = tid & 63;
  const int w    = tid >> 6;     // 0..7
  const int wm   = w >> 2;       // 0..1
  const int wn   = w & 3;        // 0..3
  const int g    = lane >> 4;
  const int ql   = lane & 15;
  const int KT   = Kdim / 64;

  fx4 acc[8][4];
#pragma unroll
  for (int i = 0; i < 8; ++i)
#pragma unroll
    for (int j = 0; j < 4; ++j) acc[i][j] = {0.f, 0.f, 0.f, 0.f};

  // prologue: tile0 fully (4 halves) + A-h0(1); wait all but last half-tile
  stage_a256(A, m0, Kdim, 0, 0, Asm);
  stage_a256(A, m0, Kdim, 0, 1, Asm);
  stage_b256(Bt, n0, Kdim, 0, 0, Bsm);
  stage_b256(Bt, n0, Kdim, 0, 1, Bsm);
  stage_a256(A, m0, Kdim, 1, 0, Asm);
  asm volatile("s_waitcnt vmcnt(2)" ::: "memory");
  __builtin_amdgcn_s_barrier();
  __builtin_amdgcn_sched_barrier(0);

  for (int t = 0; t < KT; ++t) {
    const char* Ab = Asm + (t & 1) * 32768;
    const char* Bb = Bsm + (t & 1) * 32768;
#pragma unroll
    for (int p = 0; p < 4; ++p) {
      const int ah = p >> 1, kk = p & 1;
      if (p == 0 && t + 1 < KT) stage_a256(A, m0, Kdim, t + 1, 1, Asm);
      if (p == 1 && t + 1 < KT) stage_b256(Bt, n0, Kdim, t + 1, 0, Bsm);
      if (p == 2 && t + 1 < KT) stage_b256(Bt, n0, Kdim, t + 1, 1, Bsm);
      if (p == 3 && t + 2 < KT) stage_a256(A, m0, Kdim, t + 2, 0, Asm);
      __builtin_amdgcn_sched_barrier(0);

      bfx8 af[4], bf[4];
      const int cbv = kk * 64 + g * 16;
#pragma unroll
      for (int j = 0; j < 4; ++j) {
        int arow = wm * 128 + (ah * 4 + j) * 16 + ql;
        af[j] = *(const bfx8*)(Ab + arow * 128 + (cbv ^ ((arow & 7) << 4)));
      }
#pragma unroll
      for (int nf = 0; nf < 4; ++nf) {
        int brow = wn * 64 + nf * 16 + ql;
        bf[nf] = *(const bfx8*)(Bb + brow * 128 + (cbv ^ ((brow & 7) << 4)));
      }
      __builtin_amdgcn_sched_barrier(0);
      __builtin_amdgcn_s_barrier();
      asm volatile("s_waitcnt lgkmcnt(0)" ::: "memory");
      __builtin_amdgcn_sched_barrier(0);
      __builtin_amdgcn_s_setprio(1);
#pragma unroll
      for (int j = 0; j < 4; ++j)
#pragma unroll
        for (int nf = 0; nf < 4; ++nf)
          acc[ah * 4 + j][nf] = __builtin_amdgcn_mfma_f32_16x16x32_bf16(
              af[j], bf[nf], acc[ah * 4 + j][nf], 0, 0, 0);
      __builtin_amdgcn_s_setprio(0);
      __builtin_amdgcn_s_barrier();
      __builtin_amdgcn_sched_barrier(0);
    }
    if (t + 1 < KT) {
      if (t + 2 < KT) asm volatile("s_waitcnt vmcnt(2)" ::: "memory");
      else            asm volatile("s_waitcnt vmcnt(0)" ::: "memory");
      __builtin_amdgcn_s_barrier();
      __builtin_amdgcn_sched_barrier(0);
    }
  }

#pragma unroll
  for (int mf = 0; mf < 8; ++mf) {
#pragma unroll
    for (int nf = 0; nf < 4; ++nf) {
      int col = n0 + wn * 64 + nf * 16 + ql;
      float bvl = bias[col];
#pragma unroll
      for (int r = 0; r < 4; ++r) {
        int rowg = m0 + wm * 128 + mf * 16 + g * 4 + r;
        float v = acc[mf][nf][r] + bvl;
        if (MODE == 2) v = 0.5f * v * (1.0f + erff(v * 0.70710678118654752f));
        if (MODE == 1) ((float*)out)[(size_t)rowg * Ndim + col] = v;
        else          ((__bf16*)out)[(size_t)rowg * Ndim + col] = (__bf16)v;
      }
    }
  }
}

template<int MODE>
__global__ __launch_bounds__(512)
void gemm256_kernel(const __bf16* __restrict__ A, const __bf16* __restrict__ Bt,
                    const float* __restrict__ bias, void* __restrict__ out,
                    int Ndim, int Kdim) {
  gemm256_body<MODE>(A, Bt, bias, out, Ndim, Kdim,
                     blockIdx.y * 256, blockIdx.x * 256);
}

struct QKVArgs {
  const __bf16* A[3]; const __bf16* Bt[3]; const float* bias[3]; __bf16* out[3];
};

__global__ __launch_bounds__(512)
void qkv256_kernel(QKVArgs args, int Ndim, int Kdim) {
  int z = blockIdx.z;
  gemm256_body<0>(args.A[z], args.Bt[z], args.bias[z], (void*)args.out[z],
                  Ndim, Kdim, blockIdx.y * 256, blockIdx.x * 256);
}

// --------------------------------------------------------- flash attention
// (round-8 validated, UNCHANGED)
__global__ __launch_bounds__(512)
void attn_kernel(const __bf16* __restrict__ Qb, const __bf16* __restrict__ Kb,
                 const __bf16* __restrict__ Vt, const float* __restrict__ mask,
                 __bf16* __restrict__ ctx) {
  __shared__ alignas(16) __bf16 Qs[128 * 64];
  __shared__ alignas(16) __bf16 Ks[2 * 64 * 64];
  __shared__ alignas(16) __bf16 Vs[2 * 64 * 64];
  __shared__ alignas(16) __bf16 Ps[8 * 16 * 64];

  const int tid  = threadIdx.x;
  const int lane = tid & 63;
  const int w    = tid >> 6;
  const int g    = lane >> 4;
  const int ql   = lane & 15;
  const int bh   = blockIdx.y;
  const int b    = bh >> 4;
  const int h    = bh & 15;
  const int q0   = blockIdx.x * 128;

  const size_t kbase  = ((size_t)(b * S_)) * D_ + h * DH_;
  const size_t vtbase = (size_t)bh * DH_ * S_;

  const size_t qbase = ((size_t)(b * S_) + q0) * D_ + h * DH_;
#pragma unroll
  for (int i = 0; i < 2; ++i) {
    int o   = tid * 16 + i * 8192;
    int row = o >> 7, cb = o & 127;
    int cbs = cb ^ ((row & 7) << 4);
    gload_lds16((const char*)Qb + (qbase + (size_t)row * D_) * 2 + cbs, (char*)Qs + o);
  }
  {
    int o   = tid * 16;
    int row = o >> 7, cb = o & 127;
    int cbs = cb ^ ((row & 7) << 4);
    gload_lds16((const char*)Kb + (kbase + (size_t)row * D_) * 2 + cbs, (char*)Ks + o);
    gload_lds16((const char*)Vt + (vtbase + (size_t)row * S_) * 2 + cbs, (char*)Vs + o);
  }
  __syncthreads();

  bfx8 aq[2];
  {
    int row = w * 16 + ql;
#pragma unroll
    for (int kk = 0; kk < 2; ++kk) {
      int cb = kk * 64 + g * 16;
      aq[kk] = *(const bfx8*)((const char*)Qs + row * 128 + (cb ^ ((row & 7) << 4)));
    }
  }

  float mrun = -1e30f, lrun = 0.f;
  fx4 acc[4];
#pragma unroll
  for (int d = 0; d < 4; ++d) acc[d] = {0.f, 0.f, 0.f, 0.f};

  char* pw = (char*)Ps + w * 2048;
  const int NT = S_ / 64;

  for (int t = 0; t < NT; ++t) {
    const int kv0 = t * 64;
    if (t < NT - 1) {
      int o   = tid * 16;
      int row = o >> 7, cb = o & 127;
      int cbs = cb ^ ((row & 7) << 4);
      int nkv = kv0 + 64;
      gload_lds16((const char*)Kb + (kbase + (size_t)(nkv + row) * D_) * 2 + cbs,
                  (char*)Ks + ((t + 1) & 1) * 8192 + o);
      gload_lds16((const char*)Vt + (vtbase + (size_t)row * S_ + nkv) * 2 + cbs,
                  (char*)Vs + ((t + 1) & 1) * 8192 + o);
    }
    __builtin_amdgcn_sched_barrier(0);
    if (t > 0) {
      if (t < NT - 1) asm volatile("s_waitcnt vmcnt(2)" ::: "memory");
      else            asm volatile("s_waitcnt vmcnt(0)" ::: "memory");
      __builtin_amdgcn_s_barrier();
      __builtin_amdgcn_sched_barrier(0);
    }
    const char* Kc = (const char*)Ks + (t & 1) * 8192;
    const char* Vc = (const char*)Vs + (t & 1) * 8192;

    fx4 sc[4];
#pragma unroll
    for (int nf = 0; nf < 4; ++nf) sc[nf] = {0.f, 0.f, 0.f, 0.f};
#pragma unroll
    for (int kk = 0; kk < 2; ++kk) {
      const int cb = kk * 64 + g * 16;
      bfx8 bk[4];
#pragma unroll
      for (int nf = 0; nf < 4; ++nf) {
        int row = nf * 16 + ql;
        bk[nf] = *(const bfx8*)(Kc + row * 128 + (cb ^ ((row & 7) << 4)));
      }
#pragma unroll
      for (int nf = 0; nf < 4; ++nf)
        sc[nf] = __builtin_amdgcn_mfma_f32_16x16x32_bf16(bk[nf], aq[kk], sc[nf], 0, 0, 0);
    }

    float sv[4][4];
#pragma unroll
    for (int nf = 0; nf < 4; ++nf) {
      float4 mk = *(const float4*)(mask + b * S_ + kv0 + nf * 16 + g * 4);
      sv[nf][0] = sc[nf][0] * 0.125f + mk.x;
      sv[nf][1] = sc[nf][1] * 0.125f + mk.y;
      sv[nf][2] = sc[nf][2] * 0.125f + mk.z;
      sv[nf][3] = sc[nf][3] * 0.125f + mk.w;
    }
    float mx = sv[0][0];
#pragma unroll
    for (int nf = 0; nf < 4; ++nf)
#pragma unroll
      for (int r = 0; r < 4; ++r) mx = fmaxf(mx, sv[nf][r]);
    mx = fmaxf(mx, __shfl_xor(mx, 16));
    mx = fmaxf(mx, __shfl_xor(mx, 32));
    float mnew  = fmaxf(mrun, mx);
    float alpha = __expf(mrun - mnew);
    float rs = 0.f;
#pragma unroll
    for (int nf = 0; nf < 4; ++nf)
#pragma unroll
      for (int r = 0; r < 4; ++r) {
        float p = __expf(sv[nf][r] - mnew);
        sv[nf][r] = p; rs += p;
      }
    rs += __shfl_xor(rs, 16);
    rs += __shfl_xor(rs, 32);
    lrun = lrun * alpha + rs;
    mrun = mnew;

#pragma unroll
    for (int nf = 0; nf < 4; ++nf) {
      bfx4 pv;
      pv[0] = (__bf16)sv[nf][0]; pv[1] = (__bf16)sv[nf][1];
      pv[2] = (__bf16)sv[nf][2]; pv[3] = (__bf16)sv[nf][3];
      int c = (nf * 32 + g * 8) ^ ((ql & 7) << 4);
      *(bfx4*)(pw + ql * 128 + c) = pv;
    }

    float af[4];
#pragma unroll
    for (int r = 0; r < 4; ++r) af[r] = __shfl(alpha, g * 4 + r);
#pragma unroll
    for (int d = 0; d < 4; ++d)
#pragma unroll
      for (int r = 0; r < 4; ++r) acc[d][r] *= af[r];

    asm volatile("s_waitcnt lgkmcnt(0)" ::: "memory");
    __builtin_amdgcn_sched_barrier(0);

#pragma unroll
    for (int kk = 0; kk < 2; ++kk) {
      int prow = ql;
      int cb   = kk * 64 + g * 16;
      bfx8 ap  = *(const bfx8*)((const char*)pw + prow * 128 + (cb ^ ((prow & 7) << 4)));
#pragma unroll
      for (int d = 0; d < 4; ++d) {
        int vrow = d * 16 + ql;
        bfx8 bv  = *(const bfx8*)(Vc + vrow * 128 + (cb ^ ((vrow & 7) << 4)));
        acc[d] = __builtin_amdgcn_mfma_f32_16x16x32_bf16(ap, bv, acc[d], 0, 0, 0);
      }
    }

    __builtin_amdgcn_s_barrier();
    __builtin_amdgcn_sched_barrier(0);
  }

  float linv = 1.0f / lrun;
#pragma unroll
  for (int r = 0; r < 4; ++r) {
    float inv = __shfl(linv, g * 4 + r);
    int qrow = q0 + w * 16 + g * 4 + r;
    size_t base = ((size_t)(b * S_) + qrow) * D_ + h * DH_;
#pragma unroll
    for (int d = 0; d < 4; ++d)
      ctx[base + d * 16 + ql] = (__bf16)(acc[d][r] * inv);
  }
}

// -------------------------------------------- residual + LayerNorm (row=1024)
template<bool WRITE_BF16>
__global__ __launch_bounds__(256)
void ln_kernel(const float* __restrict__ a, const float* __restrict__ b,
               const float* __restrict__ g, const float* __restrict__ beta,
               float* __restrict__ outf, __bf16* __restrict__ outb) {
  const int row = blockIdx.x;
  const int tid = threadIdx.x;
  const size_t base = (size_t)row * D_;
  float4 xa = *(const float4*)(a + base + tid * 4);
  float4 xb = *(const float4*)(b + base + tid * 4);
  float x[4] = {xa.x + xb.x, xa.y + xb.y, xa.z + xb.z, xa.w + xb.w};
  float s = x[0] + x[1] + x[2] + x[3];
#pragma unroll
  for (int m = 1; m < 64; m <<= 1) s += __shfl_xor(s, m);
  __shared__ float red[8];
  if ((tid & 63) == 0) red[tid >> 6] = s;
  __syncthreads();
  float mu = (red[0] + red[1] + red[2] + red[3]) * (1.0f / D_);
  float v0 = 0.f;
#pragma unroll
  for (int i = 0; i < 4; ++i) { float d = x[i] - mu; v0 += d * d; }
#pragma unroll
  for (int m = 1; m < 64; m <<= 1) v0 += __shfl_xor(v0, m);
  if ((tid & 63) == 0) red[4 + (tid >> 6)] = v0;
  __syncthreads();
  float var = (red[4] + red[5] + red[6] + red[7]) * (1.0f / D_);
  float rs = rsqrtf(var + 1e-12f);
#pragma unroll
  for (int i = 0; i < 4; ++i) {
    int col = tid * 4 + i;
    x[i] = (x[i] - mu) * rs * g[col] + beta[col];
  }
  *(float4*)(outf + base + tid * 4) = make_float4(x[0], x[1], x[2], x[3]);
  if (WRITE_BF16) {
    bfx4 o;
    o[0] = (__bf16)x[0]; o[1] = (__bf16)x[1]; o[2] = (__bf16)x[2]; o[3] = (__bf16)x[3];
    *(bfx4*)(outb + base + tid * 4) = o;
  }
}

// ---------------------------------------------------------------- launch
extern "C" void kernel_launch(void* const* d_in, const int* in_sizes, int n_in,
                              void* d_out, int out_size, void* d_ws, size_t ws_size,
                              hipStream_t stream) {
  const float* query    = (const float*)d_in[0];
  const float* key_in   = (const float*)d_in[1];
  const float* value_in = (const float*)d_in[2];
  const float* mask     = (const float*)d_in[3];
  const float* Wq = (const float*)d_in[4];  const float* bq = (const float*)d_in[5];
  const float* Wk = (const float*)d_in[6];  const float* bk = (const float*)d_in[7];
  const float* Wv = (const float*)d_in[8];  const float* bv = (const float*)d_in[9];
  const float* Wo = (const float*)d_in[10]; const float* bo = (const float*)d_in[11];
  const float* ln1g = (const float*)d_in[12]; const float* ln1b = (const float*)d_in[13];
  const float* Wi = (const float*)d_in[14]; const float* bi = (const float*)d_in[15];
  const float* Wd = (const float*)d_in[16]; const float* bd = (const float*)d_in[17];
  const float* ln2g = (const float*)d_in[18]; const float* ln2b = (const float*)d_in[19];

  char* ws = (char*)d_ws;
  const size_t MB = 1ull << 20;
  if (ws_size < 112 * MB) return;

  __bf16* xq   = (__bf16*)(ws + 0 * MB);
  __bf16* xk   = (__bf16*)(ws + 8 * MB);
  __bf16* xv   = (__bf16*)(ws + 16 * MB);
  float*  alin = (float*)(ws + 0 * MB);
  __bf16* x1b  = (__bf16*)(ws + 16 * MB);
  __bf16* qb   = (__bf16*)(ws + 24 * MB);
  __bf16* kb   = (__bf16*)(ws + 32 * MB);
  __bf16* vb   = (__bf16*)(ws + 40 * MB);
  __bf16* vt   = (__bf16*)(ws + 48 * MB);
  __bf16* inter= (__bf16*)(ws + 24 * MB);
  __bf16* ctxb = (__bf16*)(ws + 56 * MB);
  float*  ff   = (float*)(ws + 56 * MB);
  float*  x1f  = (float*)(ws + 72 * MB);
  __bf16* wqt  = (__bf16*)(ws + 88 * MB);
  __bf16* wkt  = (__bf16*)(ws + 90 * MB);
  __bf16* wvt  = (__bf16*)(ws + 92 * MB);
  __bf16* wot  = (__bf16*)(ws + 94 * MB);
  __bf16* wit  = (__bf16*)(ws + 96 * MB);
  __bf16* wdt  = (__bf16*)(ws + 104 * MB);

  dim3 b256(256);
  dim3 tblk(32, 8);
  const int n1 = M_ * D_;

  to_bf16_kernel<<<dim3(n1 / 1024), b256, 0, stream>>>(query, xq, n1);
  to_bf16_kernel<<<dim3(n1 / 1024), b256, 0, stream>>>(key_in, xk, n1);
  to_bf16_kernel<<<dim3(n1 / 1024), b256, 0, stream>>>(value_in, xv, n1);

  transpose_conv_kernel<<<dim3(D_ / 32, D_ / 32), tblk, 0, stream>>>(Wq, wqt, D_, D_);
  transpose_conv_kernel<<<dim3(D_ / 32, D_ / 32), tblk, 0, stream>>>(Wk, wkt, D_, D_);
  transpose_conv_kernel<<<dim3(D_ / 32, D_ / 32), tblk, 0, stream>>>(Wv, wvt, D_, D_);
  transpose_conv_kernel<<<dim3(D_ / 32, D_ / 32), tblk, 0, stream>>>(Wo, wot, D_, D_);
  transpose_conv_kernel<<<dim3(DFF_ / 32, D_ / 32), tblk, 0, stream>>>(Wi, wit, D_, DFF_);
  transpose_conv_kernel<<<dim3(D_ / 32, DFF_ / 32), tblk, 0, stream>>>(Wd, wdt, DFF_, D_);

  QKVArgs qa;
  qa.A[0] = xq;  qa.A[1] = xk;  qa.A[2] = xv;
  qa.Bt[0] = wqt; qa.Bt[1] = wkt; qa.Bt[2] = wvt;
  qa.bias[0] = bq; qa.bias[1] = bk; qa.bias[2] = bv;
  qa.out[0] = qb; qa.out[1] = kb; qa.out[2] = vb;
  qkv256_kernel<<<dim3(D_ / 256, M_ / 256, 3), dim3(512), 131072, stream>>>(qa, D_, D_);

  transpose_v_kernel<<<dim3(S_ / 32, 2, B_ * H_), tblk, 0, stream>>>(vb, vt);

  attn_kernel<<<dim3(S_ / 128, B_ * H_), dim3(512), 0, stream>>>(qb, kb, vt, mask, ctxb);

  gemm_kernel<1, 64><<<dim3(D_ / 64, M_ / 128), b256, 0, stream>>>(ctxb, wot, bo, (void*)alin, D_, D_);

  ln_kernel<true><<<dim3(M_), b256, 0, stream>>>(alin, query, ln1g, ln1b, x1f, x1b);

  gemm256_kernel<2><<<dim3(DFF_ / 256, M_ / 256), dim3(512), 131072, stream>>>(x1b, wit, bi, (void*)inter, DFF_, D_);

  gemm_kernel<1, 64><<<dim3(D_ / 64, M_ / 128), b256, 0, stream>>>(inter, wdt, bd, (void*)ff, D_, DFF_);

  ln_kernel<false><<<dim3(M_), b256, 0, stream>>>(ff, x1f, ln2g, ln2b, (float*)d_out, nullptr);
}